// Round 11
// baseline (65.263 us; speedup 1.0000x reference)
//
#include <hip/hip_runtime.h>
#include <hip/hip_fp16.h>

#define B_ 4
#define F_ 2
#define C_ 16
#define H_ 48
#define W_ 160
#define D_ 96
#define HW_ (H_*W_)
#define PIX_ 64            // pixels per block (one wave = 64 px at one depth-group)
#define GRP_ 8             // depth groups per block (PIX_*GRP_ = 512 threads)
#define BINS_ (D_/GRP_)    // 12 bins per group
#define NCHUNK_ (HW_/PIX_) // 120
#define NROWS_ 12          // staged image rows (12*160*32B = 60KB LDS)
#define ROWU4_ (W_*2)      // uint4 per image row (160 px * 32B / 16B)

// Prep: mats (block 0) + transpose/fp16 of cur and look.
// 2 threads per pixel (8 channels each) -> 720 blocks for TLP.
__global__ __launch_bounds__(256) void prep_kernel(
    const float* __restrict__ cur, const float* __restrict__ look,
    const float* __restrict__ poses, const float* __restrict__ Kmat,
    __half* __restrict__ curH, __half* __restrict__ lookH,
    float* __restrict__ mats)
{
  int tid = threadIdx.x;
  int bid = blockIdx.x;
  if (bid == 0 && tid < B_*F_) {
    int t = tid, b = t / F_;
    const float* T  = poses + t*16;
    const float* Kb = Kmat + b*16;
    float sum = 0.f;
    #pragma unroll
    for (int i = 0; i < 16; ++i) sum += T[i];
    #pragma unroll
    for (int i = 0; i < 3; ++i) {
      #pragma unroll
      for (int j = 0; j < 4; ++j) {
        float v = 0.f;
        #pragma unroll
        for (int k = 0; k < 4; ++k) v += Kb[i*4+k] * T[k*4+j];
        mats[t*16 + i*4 + j] = v;
      }
    }
    mats[t*16 + 12] = (sum != 0.f) ? 1.f : 0.f;
  }
  int px_l = tid & 127;
  int h    = tid >> 7;                 // 0 or 1 (channel half)
  int gp   = bid*128 + px_l;           // global pixel id over cur then look
  const float* src;
  __half* dst;
  int hw, c0 = h*8;
  if (gp < B_*HW_) {
    hw = gp % HW_;
    int s = gp / HW_;
    src = cur + (size_t)s*C_*HW_ + hw;
    dst = curH + (size_t)gp*C_ + c0;
  } else {
    int j = gp - B_*HW_;
    hw = j % HW_;
    int s = j / HW_;
    src = look + (size_t)s*C_*HW_ + hw;
    dst = lookH + (size_t)j*C_ + c0;
  }
  __half2 hh[4];
  #pragma unroll
  for (int j = 0; j < 4; ++j)
    hh[j] = __floats2half2_rn(src[(size_t)(c0+2*j)*HW_], src[(size_t)(c0+2*j+1)*HW_]);
  *reinterpret_cast<uint4*>(dst) = *reinterpret_cast<uint4*>(&hh[0]);
}

// Fused cost + finalize, LDS-staged lookup band.
// Block = 64 pixels x 8 depth-groups. Per frame: (A) projection-only pass
// finds the block's sampled y-band; (B) stage the band (full rows) into LDS
// and sample from it. lds-vs-global choice is BLOCK-UNIFORM; per-iteration
// tap regs are fully written every iteration (no loop-carried cond. state).
__global__ __launch_bounds__(512, 4) void fused_kernel(
    const __half* __restrict__ curH, const __half* __restrict__ lookH,
    const float* __restrict__ mats, const float* __restrict__ invK,
    const float* __restrict__ dbins,
    float* __restrict__ cost, float* __restrict__ missing)
{
  __shared__ uint4 stage[NROWS_*ROWU4_];
  __shared__ float lmaxs[GRP_][PIX_];
  __shared__ int s_ymin, s_ymax;

  int tid = threadIdx.x;
  int pix = tid & (PIX_-1);
  int grp = tid >> 6;                 // 0..7 (wave index)
  int bid = blockIdx.x;
  int chunk = bid % NCHUNK_;
  int b = bid / NCHUNK_;
  int hw = chunk*PIX_ + pix;
  int x = hw % W_, y = hw / W_;
  size_t obase = ((size_t)(b*D_ + grp*BINS_))*HW_ + hw;
  bool interior = (x >= 2 && x < W_-2 && y >= 2 && y < H_-2);

  // per-thread invariants (unconditional; hw always valid)
  const float* iK = invK + b*16;
  float xf = (float)x, yf = (float)y;
  float r0 = iK[0]*xf + iK[1]*yf + iK[2];
  float r1 = iK[4]*xf + iK[5]*yf + iK[6];
  float r2 = iK[8]*xf + iK[9]*yf + iK[10];
  __half2 cc2[8];
  {
    const uint4* cur4 = reinterpret_cast<const uint4*>(curH + (size_t)(b*HW_ + hw)*C_);
    *reinterpret_cast<uint4*>(&cc2[0]) = cur4[0];
    *reinterpret_cast<uint4*>(&cc2[4]) = cur4[1];
  }
  float dep[BINS_];
  #pragma unroll
  for (int dd = 0; dd < BINS_; ++dd) dep[dd] = dbins[grp*BINS_ + dd];

  float res[BINS_];
  #pragma unroll
  for (int dd = 0; dd < BINS_; ++dd) res[dd] = 0.f;
  float diffs0[BINS_];
  #pragma unroll
  for (int dd = 0; dd < BINS_; ++dd) diffs0[dd] = 0.f;
  float lmax = 0.f;

  for (int f = 0; f < F_; ++f) {
    const float* Mt = mats + (b*F_+f)*16;
    float M0=Mt[0], M1=Mt[1], M2 =Mt[2],  M3 =Mt[3];
    float M4=Mt[4], M5=Mt[5], M6 =Mt[6],  M7 =Mt[7];
    float M8=Mt[8], M9=Mt[9], M10=Mt[10], M11=Mt[11];
    float valid = Mt[12];
    const __half* fbase = lookH + (size_t)((b*F_+f)*HW_)*C_;

    // --- phase A: projection-only pass -> per-thread clamped-yi range ---
    int my_ymin = H_, my_ymax = -1;
    if (interior) {
      #pragma unroll
      for (int dd = 0; dd < BINS_; ++dd) {
        float p0 = dep[dd]*r0, p1 = dep[dd]*r1, p2 = dep[dd]*r2;
        float camy = M4*p0 + M5*p1 + M6 *p2 + M7;
        float camz = M8*p0 + M9*p1 + M10*p2 + M11;
        float z  = camz + 1e-7f;
        float py = camy / z;
        float y0 = floorf(py);
        int yi = min(max((int)y0, 0), H_-2);
        my_ymin = min(my_ymin, yi);
        my_ymax = max(my_ymax, yi);
      }
    }
    if (tid == 0) { s_ymin = H_; s_ymax = -1; }
    __syncthreads();
    atomicMin(&s_ymin, my_ymin);
    atomicMax(&s_ymax, my_ymax);
    __syncthreads();
    int ymin = s_ymin, ymax = s_ymax;
    int nr = ymax + 2 - ymin;
    bool lds_use = (ymax >= 0) && (nr <= NROWS_);   // block-uniform
    if (lds_use) {
      const uint4* fsrc = reinterpret_cast<const uint4*>(fbase) + (size_t)ymin*ROWU4_;
      for (int i = tid; i < nr*ROWU4_; i += 512) stage[i] = fsrc[i];
    }
    __syncthreads();

    // --- phase B: sample ---
    if (interior) {
      #pragma unroll
      for (int dd = 0; dd < BINS_; ++dd) {
        float p0 = dep[dd]*r0, p1 = dep[dd]*r1, p2 = dep[dd]*r2;
        float camx = M0*p0 + M1*p1 + M2 *p2 + M3;
        float camy = M4*p0 + M5*p1 + M6 *p2 + M7;
        float camz = M8*p0 + M9*p1 + M10*p2 + M11;
        float z  = camz + 1e-7f;
        float px = camx / z;
        float py = camy / z;
        bool ok = (valid != 0.f) && (px >= 2.f) && (px <= (float)(W_-2))
                                 && (py >= 2.f) && (py <= (float)(H_-2));
        float x0 = floorf(px), y0 = floorf(py);
        float fx = px - x0, fy = py - y0;
        fx = fminf(fmaxf(fx, 0.f), 1.f);
        fy = fminf(fmaxf(fy, 0.f), 1.f);
        int xi = min(max((int)x0, 0), W_-2);
        int yi = min(max((int)y0, 0), H_-2);
        uint4 t[8];
        if (lds_use) {
          int bi = ((yi - ymin)*W_ + xi)*2;
          #pragma unroll
          for (int i = 0; i < 4; ++i) t[i]   = stage[bi + i];
          #pragma unroll
          for (int i = 0; i < 4; ++i) t[4+i] = stage[bi + ROWU4_ + i];
        } else {
          const uint4* rr0 = reinterpret_cast<const uint4*>(fbase + ((size_t)(yi*W_ + xi))*C_);
          const uint4* rr1 = rr0 + (W_*C_)/8;
          #pragma unroll
          for (int i = 0; i < 4; ++i) t[i]   = rr0[i];
          #pragma unroll
          for (int i = 0; i < 4; ++i) t[4+i] = rr1[i];
        }
        __half2 w00h = __float2half2_rn((1.f-fx)*(1.f-fy));
        __half2 w10h = __float2half2_rn(fx*(1.f-fy));
        __half2 w01h = __float2half2_rn((1.f-fx)*fy);
        __half2 w11h = __float2half2_rn(fx*fy);
        const __half2* a00 = reinterpret_cast<const __half2*>(&t[0]);
        const __half2* a10 = reinterpret_cast<const __half2*>(&t[2]);
        const __half2* a01 = reinterpret_cast<const __half2*>(&t[4]);
        const __half2* a11 = reinterpret_cast<const __half2*>(&t[6]);
        __half2 acc0 = __float2half2_rn(0.f);
        __half2 acc1 = __float2half2_rn(0.f);
        #pragma unroll
        for (int i = 0; i < 8; ++i) {
          __half2 v = __hmul2(w00h, a00[i]);
          v = __hfma2(w10h, a10[i], v);
          v = __hfma2(w01h, a01[i], v);
          v = __hfma2(w11h, a11[i], v);
          __half2 dsub = __habs2(__hsub2(v, cc2[i]));
          if (i & 1) acc1 = __hadd2(acc1, dsub);
          else       acc0 = __hadd2(acc0, dsub);
        }
        float2 f0 = __half22float2(acc0);
        float2 f1 = __half22float2(acc1);
        float s = (f0.x + f0.y) + (f1.x + f1.y);
        float diffs = s * (1.f/16.f);
        diffs = ok ? diffs : 0.f;
        if (f == 0) {
          diffs0[dd] = diffs;
        } else {
          float c0v = diffs0[dd];
          float cnt = ((c0v > 0.f) ? 1.f : 0.f) + ((diffs > 0.f) ? 1.f : 0.f);
          float r = (c0v + diffs) / (cnt + 1e-7f);
          res[dd] = r;
          lmax = fmaxf(lmax, r);
        }
      }
    }
    __syncthreads();   // protect stage/s_ymin before next frame
  }

  // per-pixel max over the 8 depth-groups
  lmaxs[grp][pix] = lmax;
  __syncthreads();
  float pmax = lmaxs[0][pix];
  #pragma unroll
  for (int g = 1; g < GRP_; ++g) pmax = fmaxf(pmax, lmaxs[g][pix]);

  // write cost (missing-filled) + missing, straight from registers
  #pragma unroll
  for (int dd = 0; dd < BINS_; ++dd) {
    size_t o = obase + (size_t)dd*HW_;
    float v = res[dd];
    float miss = (v == 0.f) ? 1.f : 0.f;
    cost[o]    = miss ? pmax : v;
    missing[o] = miss;
  }
}

extern "C" void kernel_launch(void* const* d_in, const int* in_sizes, int n_in,
                              void* d_out, int out_size, void* d_ws, size_t ws_size,
                              hipStream_t stream) {
  const float* cur   = (const float*)d_in[0];
  const float* look  = (const float*)d_in[1];
  const float* poses = (const float*)d_in[2];
  const float* Km    = (const float*)d_in[3];
  const float* invK  = (const float*)d_in[4];
  const float* dbins = (const float*)d_in[5];

  float* out_cost = (float*)d_out;
  float* out_miss = out_cost + (size_t)B_*D_*HW_;

  char*   ws    = (char*)d_ws;
  float*  mats  = (float*)ws;                                       // 128 floats
  __half* curH  = (__half*)(ws + 1024);                             // B*HW*C f16
  __half* lookH = (__half*)(ws + 1024 + (size_t)B_*HW_*C_*2);       // B*F*HW*C f16

  prep_kernel<<<(B_*HW_ + B_*F_*HW_)/128, 256, 0, stream>>>(
      cur, look, poses, Km, curH, lookH, mats);
  fused_kernel<<<B_*NCHUNK_, 512, 0, stream>>>(
      curH, lookH, mats, invK, dbins, out_cost, out_miss);
}

// Round 12
// 52.751 us; speedup vs baseline: 1.2372x; 1.2372x over previous
//
#include <hip/hip_runtime.h>
#include <hip/hip_fp16.h>

#define B_ 4
#define F_ 2
#define C_ 16
#define H_ 48
#define W_ 160
#define D_ 96
#define HW_ (H_*W_)
#define PIX_ 64            // pixels per block (one wave = 64 px at one depth-group)
#define GRP_ 8             // depth groups per block (PIX_*GRP_ = 512 threads)
#define BINS_ (D_/GRP_)    // 12 bins per group
#define NCHUNK_ (HW_/PIX_) // 120

// Prep: mats (block 0) + cur transpose ([px][16ch] fp16) + look transpose into
// PLANAR-HALF fp16 layout: per slice, plane0 = channels 0-7, plane1 = 8-15,
// each [HW][8ch] (16B per pixel) -> tap reads at 16B lane-stride.
__global__ __launch_bounds__(256) void prep_kernel(
    const float* __restrict__ cur, const float* __restrict__ look,
    const float* __restrict__ poses, const float* __restrict__ Kmat,
    __half* __restrict__ curH, __half* __restrict__ lookP,
    float* __restrict__ mats)
{
  int tid = threadIdx.x;
  int bid = blockIdx.x;
  if (bid == 0 && tid < B_*F_) {
    int t = tid, b = t / F_;
    const float* T  = poses + t*16;
    const float* Kb = Kmat + b*16;
    float sum = 0.f;
    #pragma unroll
    for (int i = 0; i < 16; ++i) sum += T[i];
    #pragma unroll
    for (int i = 0; i < 3; ++i) {
      #pragma unroll
      for (int j = 0; j < 4; ++j) {
        float v = 0.f;
        #pragma unroll
        for (int k = 0; k < 4; ++k) v += Kb[i*4+k] * T[k*4+j];
        mats[t*16 + i*4 + j] = v;
      }
    }
    mats[t*16 + 12] = (sum != 0.f) ? 1.f : 0.f;
  }
  int px_l = tid & 127;
  int h    = tid >> 7;                 // 0 or 1 (channel half / plane)
  int gp   = bid*128 + px_l;           // global pixel id over cur then look
  const float* src;
  __half* dst;
  int hw, c0 = h*8;
  if (gp < B_*HW_) {
    hw = gp % HW_;
    int s = gp / HW_;
    src = cur + (size_t)s*C_*HW_ + hw;
    dst = curH + (size_t)gp*C_ + c0;                    // interleaved [px][16]
  } else {
    int j = gp - B_*HW_;
    hw = j % HW_;
    int s = j / HW_;
    src = look + (size_t)s*C_*HW_ + hw;
    dst = lookP + ((size_t)(s*2 + h)*HW_ + hw)*8;       // planar [s][plane][px][8]
  }
  __half2 hh[4];
  #pragma unroll
  for (int j = 0; j < 4; ++j)
    hh[j] = __floats2half2_rn(src[(size_t)(c0+2*j)*HW_], src[(size_t)(c0+2*j+1)*HW_]);
  *reinterpret_cast<uint4*>(dst) = *reinterpret_cast<uint4*>(&hh[0]);
}

// Fused cost + finalize. Block = 64 pixels x 8 depth-groups (12 bins each).
// Round-9 structure; taps from planar-half layout (16B lane-stride loads).
__global__ __launch_bounds__(512, 4) void fused_kernel(
    const __half* __restrict__ curH, const __half* __restrict__ lookP,
    const float* __restrict__ mats, const float* __restrict__ invK,
    const float* __restrict__ dbins,
    float* __restrict__ cost, float* __restrict__ missing)
{
  int tid = threadIdx.x;
  int pix = tid & (PIX_-1);
  int grp = tid >> 6;                 // 0..7 (wave index)
  int bid = blockIdx.x;
  int chunk = bid % NCHUNK_;
  int b = bid / NCHUNK_;
  int hw = chunk*PIX_ + pix;
  int x = hw % W_, y = hw / W_;
  size_t obase = ((size_t)(b*D_ + grp*BINS_))*HW_ + hw;

  float res[BINS_];
  #pragma unroll
  for (int dd = 0; dd < BINS_; ++dd) res[dd] = 0.f;
  float lmax = 0.f;
  bool interior = (x >= 2 && x < W_-2 && y >= 2 && y < H_-2);
  if (interior) {
    const float* iK = invK + b*16;
    float xf = (float)x, yf = (float)y;
    float r0 = iK[0]*xf + iK[1]*yf + iK[2];
    float r1 = iK[4]*xf + iK[5]*yf + iK[6];
    float r2 = iK[8]*xf + iK[9]*yf + iK[10];
    __half2 cc2[8];
    {
      const uint4* cur4 = reinterpret_cast<const uint4*>(curH + (size_t)(b*HW_ + hw)*C_);
      *reinterpret_cast<uint4*>(&cc2[0]) = cur4[0];
      *reinterpret_cast<uint4*>(&cc2[4]) = cur4[1];
    }
    float dep[BINS_];
    #pragma unroll
    for (int dd = 0; dd < BINS_; ++dd) dep[dd] = dbins[grp*BINS_ + dd];

    float diffs0[BINS_];
    #pragma unroll
    for (int f = 0; f < F_; ++f) {
      const float* Mt = mats + (b*F_+f)*16;
      float M0=Mt[0], M1=Mt[1], M2 =Mt[2],  M3 =Mt[3];
      float M4=Mt[4], M5=Mt[5], M6 =Mt[6],  M7 =Mt[7];
      float M8=Mt[8], M9=Mt[9], M10=Mt[10], M11=Mt[11];
      float valid = Mt[12];
      const __half* pl0 = lookP + (size_t)((b*F_+f)*2)*HW_*8;  // plane0 base
      const __half* pl1 = pl0 + (size_t)HW_*8;                 // plane1 base
      #pragma unroll
      for (int dd = 0; dd < BINS_; ++dd) {
        float p0 = dep[dd]*r0, p1 = dep[dd]*r1, p2 = dep[dd]*r2;
        float camx = M0*p0 + M1*p1 + M2 *p2 + M3;
        float camy = M4*p0 + M5*p1 + M6 *p2 + M7;
        float camz = M8*p0 + M9*p1 + M10*p2 + M11;
        float z  = camz + 1e-7f;
        float px = camx / z;
        float py = camy / z;
        bool ok = (valid != 0.f) && (px >= 2.f) && (px <= (float)(W_-2))
                                 && (py >= 2.f) && (py <= (float)(H_-2));
        float x0 = floorf(px), y0 = floorf(py);
        float fx = px - x0, fy = py - y0;
        fx = fminf(fmaxf(fx, 0.f), 1.f);
        fy = fminf(fmaxf(fy, 0.f), 1.f);
        int xi = min(max((int)x0, 0), W_-2);
        int yi = min(max((int)y0, 0), H_-2);
        int offu4 = yi*W_ + xi;        // uint4 index into a plane (16B/px)
        // 8 x 16B taps; lane-stride 16B -> dense wave spans
        uint4 t[8];
        {
          const uint4* q0 = reinterpret_cast<const uint4*>(pl0) + offu4;
          const uint4* q1 = reinterpret_cast<const uint4*>(pl1) + offu4;
          t[0] = q0[0];      t[1] = q0[1];        // plane0 row0: x0, x1
          t[2] = q0[W_];     t[3] = q0[W_+1];     // plane0 row1
          t[4] = q1[0];      t[5] = q1[1];        // plane1 row0
          t[6] = q1[W_];     t[7] = q1[W_+1];     // plane1 row1
        }
        __half2 w00h = __float2half2_rn((1.f-fx)*(1.f-fy));
        __half2 w10h = __float2half2_rn(fx*(1.f-fy));
        __half2 w01h = __float2half2_rn((1.f-fx)*fy);
        __half2 w11h = __float2half2_rn(fx*fy);
        const __half2* b00 = reinterpret_cast<const __half2*>(&t[0]);
        const __half2* b10 = reinterpret_cast<const __half2*>(&t[1]);
        const __half2* b01 = reinterpret_cast<const __half2*>(&t[2]);
        const __half2* b11 = reinterpret_cast<const __half2*>(&t[3]);
        const __half2* c00 = reinterpret_cast<const __half2*>(&t[4]);
        const __half2* c10 = reinterpret_cast<const __half2*>(&t[5]);
        const __half2* c01 = reinterpret_cast<const __half2*>(&t[6]);
        const __half2* c11 = reinterpret_cast<const __half2*>(&t[7]);
        __half2 acc0 = __float2half2_rn(0.f);
        __half2 acc1 = __float2half2_rn(0.f);
        // channels 0-7 (plane0), i ascending, even->acc0 odd->acc1 (r5 order)
        #pragma unroll
        for (int i = 0; i < 4; ++i) {
          __half2 v = __hmul2(w00h, b00[i]);
          v = __hfma2(w10h, b10[i], v);
          v = __hfma2(w01h, b01[i], v);
          v = __hfma2(w11h, b11[i], v);
          __half2 dsub = __habs2(__hsub2(v, cc2[i]));
          if (i & 1) acc1 = __hadd2(acc1, dsub);
          else       acc0 = __hadd2(acc0, dsub);
        }
        // channels 8-15 (plane1)
        #pragma unroll
        for (int i = 0; i < 4; ++i) {
          __half2 v = __hmul2(w00h, c00[i]);
          v = __hfma2(w10h, c10[i], v);
          v = __hfma2(w01h, c01[i], v);
          v = __hfma2(w11h, c11[i], v);
          __half2 dsub = __habs2(__hsub2(v, cc2[4+i]));
          if (i & 1) acc1 = __hadd2(acc1, dsub);
          else       acc0 = __hadd2(acc0, dsub);
        }
        float2 f0 = __half22float2(acc0);
        float2 f1 = __half22float2(acc1);
        float s = (f0.x + f0.y) + (f1.x + f1.y);
        float diffs = s * (1.f/16.f);
        diffs = ok ? diffs : 0.f;
        if (f == 0) {
          diffs0[dd] = diffs;
        } else {
          float c0v = diffs0[dd];
          float cnt = ((c0v > 0.f) ? 1.f : 0.f) + ((diffs > 0.f) ? 1.f : 0.f);
          float r = (c0v + diffs) / (cnt + 1e-7f);
          res[dd] = r;
          lmax = fmaxf(lmax, r);
        }
      }
    }
  }

  // per-pixel max over the 8 depth-groups
  __shared__ float lmaxs[GRP_][PIX_];
  lmaxs[grp][pix] = lmax;
  __syncthreads();
  float pmax = lmaxs[0][pix];
  #pragma unroll
  for (int g = 1; g < GRP_; ++g) pmax = fmaxf(pmax, lmaxs[g][pix]);

  // write cost (missing-filled) + missing, straight from registers
  #pragma unroll
  for (int dd = 0; dd < BINS_; ++dd) {
    size_t o = obase + (size_t)dd*HW_;
    float v = res[dd];
    float miss = (v == 0.f) ? 1.f : 0.f;
    cost[o]    = miss ? pmax : v;
    missing[o] = miss;
  }
}

extern "C" void kernel_launch(void* const* d_in, const int* in_sizes, int n_in,
                              void* d_out, int out_size, void* d_ws, size_t ws_size,
                              hipStream_t stream) {
  const float* cur   = (const float*)d_in[0];
  const float* look  = (const float*)d_in[1];
  const float* poses = (const float*)d_in[2];
  const float* Km    = (const float*)d_in[3];
  const float* invK  = (const float*)d_in[4];
  const float* dbins = (const float*)d_in[5];

  float* out_cost = (float*)d_out;
  float* out_miss = out_cost + (size_t)B_*D_*HW_;

  char*   ws    = (char*)d_ws;
  float*  mats  = (float*)ws;                                       // 128 floats
  __half* curH  = (__half*)(ws + 1024);                             // B*HW*16 f16
  __half* lookP = (__half*)(ws + 1024 + (size_t)B_*HW_*C_*2);       // B*F*2*HW*8 f16

  prep_kernel<<<(B_*HW_ + B_*F_*HW_)/128, 256, 0, stream>>>(
      cur, look, poses, Km, curH, lookP, mats);
  fused_kernel<<<B_*NCHUNK_, 512, 0, stream>>>(
      curH, lookP, mats, invK, dbins, out_cost, out_miss);
}

// Round 13
// 40.577 us; speedup vs baseline: 1.6084x; 1.3000x over previous
//
#include <hip/hip_runtime.h>
#include <hip/hip_fp16.h>

#define B_ 4
#define F_ 2
#define C_ 16
#define H_ 48
#define W_ 160
#define D_ 96
#define HW_ (H_*W_)
#define PIX_ 64            // pixels per block (one wave = 64 px at one depth-group)
#define GRP_ 8             // depth groups per block (PIX_*GRP_ = 512 threads)
#define BINS_ (D_/GRP_)    // 12 bins per group
#define NCHUNK_ (HW_/PIX_) // 120

// Prep: mats (block 0) + transpose/fp16 of cur and look.
// 2 threads per pixel (8 channels each) -> 720 blocks for TLP.
__global__ __launch_bounds__(256) void prep_kernel(
    const float* __restrict__ cur, const float* __restrict__ look,
    const float* __restrict__ poses, const float* __restrict__ Kmat,
    __half* __restrict__ curH, __half* __restrict__ lookH,
    float* __restrict__ mats)
{
  int tid = threadIdx.x;
  int bid = blockIdx.x;
  if (bid == 0 && tid < B_*F_) {
    int t = tid, b = t / F_;
    const float* T  = poses + t*16;
    const float* Kb = Kmat + b*16;
    float sum = 0.f;
    #pragma unroll
    for (int i = 0; i < 16; ++i) sum += T[i];
    #pragma unroll
    for (int i = 0; i < 3; ++i) {
      #pragma unroll
      for (int j = 0; j < 4; ++j) {
        float v = 0.f;
        #pragma unroll
        for (int k = 0; k < 4; ++k) v += Kb[i*4+k] * T[k*4+j];
        mats[t*16 + i*4 + j] = v;
      }
    }
    mats[t*16 + 12] = (sum != 0.f) ? 1.f : 0.f;
  }
  int px_l = tid & 127;
  int h    = tid >> 7;                 // 0 or 1 (channel half)
  int gp   = bid*128 + px_l;           // global pixel id over cur then look
  const float* src;
  __half* dst;
  int hw, c0 = h*8;
  if (gp < B_*HW_) {
    hw = gp % HW_;
    int s = gp / HW_;
    src = cur + (size_t)s*C_*HW_ + hw;
    dst = curH + (size_t)gp*C_ + c0;
  } else {
    int j = gp - B_*HW_;
    hw = j % HW_;
    int s = j / HW_;
    src = look + (size_t)s*C_*HW_ + hw;
    dst = lookH + (size_t)j*C_ + c0;
  }
  __half2 hh[4];
  #pragma unroll
  for (int j = 0; j < 4; ++j)
    hh[j] = __floats2half2_rn(src[(size_t)(c0+2*j)*HW_], src[(size_t)(c0+2*j+1)*HW_]);
  *reinterpret_cast<uint4*>(dst) = *reinterpret_cast<uint4*>(&hh[0]);
}

// Fused cost + finalize. Block = 64 pixels x 8 depth-groups (12 bins each).
// Each WAVE = 64 consecutive pixels at one depth-group. Unconditional batched
// tap loads (rounds 6-8 lesson: no loop-carried conditional state).
// Output stores are nontemporal (no reuse; keep L2 for the gather streams).
__global__ __launch_bounds__(512, 4) void fused_kernel(
    const __half* __restrict__ curH, const __half* __restrict__ lookH,
    const float* __restrict__ mats, const float* __restrict__ invK,
    const float* __restrict__ dbins,
    float* __restrict__ cost, float* __restrict__ missing)
{
  int tid = threadIdx.x;
  int pix = tid & (PIX_-1);
  int grp = tid >> 6;                 // 0..7 (wave index)
  int bid = blockIdx.x;
  int chunk = bid % NCHUNK_;
  int b = bid / NCHUNK_;
  int hw = chunk*PIX_ + pix;
  int x = hw % W_, y = hw / W_;
  size_t obase = ((size_t)(b*D_ + grp*BINS_))*HW_ + hw;

  float res[BINS_];
  #pragma unroll
  for (int dd = 0; dd < BINS_; ++dd) res[dd] = 0.f;
  float lmax = 0.f;
  bool interior = (x >= 2 && x < W_-2 && y >= 2 && y < H_-2);
  if (interior) {
    const float* iK = invK + b*16;
    float xf = (float)x, yf = (float)y;
    float r0 = iK[0]*xf + iK[1]*yf + iK[2];
    float r1 = iK[4]*xf + iK[5]*yf + iK[6];
    float r2 = iK[8]*xf + iK[9]*yf + iK[10];
    __half2 cc2[8];
    {
      const uint4* cur4 = reinterpret_cast<const uint4*>(curH + (size_t)(b*HW_ + hw)*C_);
      *reinterpret_cast<uint4*>(&cc2[0]) = cur4[0];
      *reinterpret_cast<uint4*>(&cc2[4]) = cur4[1];
    }
    // wave-uniform projection rows (b uniform per block, f static)
    float Mv[2][13];
    #pragma unroll
    for (int f = 0; f < F_; ++f) {
      const float* Mt = mats + (b*F_+f)*16;
      #pragma unroll
      for (int i = 0; i < 13; ++i) Mv[f][i] = Mt[i];
    }
    #pragma unroll
    for (int dd = 0; dd < BINS_; ++dd) {
      float dep = dbins[grp*BINS_ + dd];
      float p0 = dep*r0, p1 = dep*r1, p2 = dep*r2;
      // --- phase 1: addresses + weights for both frames ---
      const __half* bases[F_];
      float w00f[F_], w10f[F_], w01f[F_], w11f[F_];
      bool okf[F_];
      #pragma unroll
      for (int f = 0; f < F_; ++f) {
        float camx = Mv[f][0]*p0 + Mv[f][1]*p1 + Mv[f][2] *p2 + Mv[f][3];
        float camy = Mv[f][4]*p0 + Mv[f][5]*p1 + Mv[f][6] *p2 + Mv[f][7];
        float camz = Mv[f][8]*p0 + Mv[f][9]*p1 + Mv[f][10]*p2 + Mv[f][11];
        float z  = camz + 1e-7f;
        float px = camx / z;
        float py = camy / z;
        okf[f] = (Mv[f][12] != 0.f) && (px >= 2.f) && (px <= (float)(W_-2))
                                    && (py >= 2.f) && (py <= (float)(H_-2));
        float x0 = floorf(px), y0 = floorf(py);
        float fx = px - x0, fy = py - y0;
        fx = fminf(fmaxf(fx, 0.f), 1.f);
        fy = fminf(fmaxf(fy, 0.f), 1.f);
        int xi = min(max((int)x0, 0), W_-2);
        int yi = min(max((int)y0, 0), H_-2);
        bases[f] = lookH + ((size_t)((b*F_+f)*HW_) + yi*W_ + xi)*C_;
        w00f[f] = (1.f-fx)*(1.f-fy); w10f[f] = fx*(1.f-fy);
        w01f[f] = (1.f-fx)*fy;       w11f[f] = fx*fy;
      }
      // --- phase 2: issue all 16 tap loads ---
      uint4 t[16];
      #pragma unroll
      for (int f = 0; f < F_; ++f) {
        const uint4* rr0 = reinterpret_cast<const uint4*>(bases[f]);
        const uint4* rr1 = reinterpret_cast<const uint4*>(bases[f] + W_*C_);
        #pragma unroll
        for (int i = 0; i < 4; ++i) t[f*8+i]   = rr0[i];
        #pragma unroll
        for (int i = 0; i < 4; ++i) t[f*8+4+i] = rr1[i];
      }
      // --- phase 3: fp16 interpolation + L1 diff ---
      float costsum = 0.f, cnt = 0.f;
      #pragma unroll
      for (int f = 0; f < F_; ++f) {
        __half2 w00h = __float2half2_rn(w00f[f]);
        __half2 w10h = __float2half2_rn(w10f[f]);
        __half2 w01h = __float2half2_rn(w01f[f]);
        __half2 w11h = __float2half2_rn(w11f[f]);
        const __half2* a00 = reinterpret_cast<const __half2*>(&t[f*8+0]);
        const __half2* a10 = reinterpret_cast<const __half2*>(&t[f*8+2]);
        const __half2* a01 = reinterpret_cast<const __half2*>(&t[f*8+4]);
        const __half2* a11 = reinterpret_cast<const __half2*>(&t[f*8+6]);
        __half2 acc0 = __float2half2_rn(0.f);
        __half2 acc1 = __float2half2_rn(0.f);
        #pragma unroll
        for (int i = 0; i < 8; ++i) {
          __half2 v = __hmul2(w00h, a00[i]);
          v = __hfma2(w10h, a10[i], v);
          v = __hfma2(w01h, a01[i], v);
          v = __hfma2(w11h, a11[i], v);
          __half2 dsub = __habs2(__hsub2(v, cc2[i]));
          if (i & 1) acc1 = __hadd2(acc1, dsub);
          else       acc0 = __hadd2(acc0, dsub);
        }
        float2 f0 = __half22float2(acc0);
        float2 f1 = __half22float2(acc1);
        float s = (f0.x + f0.y) + (f1.x + f1.y);
        float diffs = s * (1.f/16.f);
        diffs = okf[f] ? diffs : 0.f;
        costsum += diffs;
        cnt     += (diffs > 0.f) ? 1.f : 0.f;
      }
      float r = costsum / (cnt + 1e-7f);
      res[dd] = r;
      lmax = fmaxf(lmax, r);
    }
  }

  // per-pixel max over the 8 depth-groups
  __shared__ float lmaxs[GRP_][PIX_];
  lmaxs[grp][pix] = lmax;
  __syncthreads();
  float pmax = lmaxs[0][pix];
  #pragma unroll
  for (int g = 1; g < GRP_; ++g) pmax = fmaxf(pmax, lmaxs[g][pix]);

  // write cost (missing-filled) + missing, straight from registers (nt stores)
  #pragma unroll
  for (int dd = 0; dd < BINS_; ++dd) {
    size_t o = obase + (size_t)dd*HW_;
    float v = res[dd];
    float miss = (v == 0.f) ? 1.f : 0.f;
    __builtin_nontemporal_store(miss ? pmax : v, &cost[o]);
    __builtin_nontemporal_store(miss, &missing[o]);
  }
}

extern "C" void kernel_launch(void* const* d_in, const int* in_sizes, int n_in,
                              void* d_out, int out_size, void* d_ws, size_t ws_size,
                              hipStream_t stream) {
  const float* cur   = (const float*)d_in[0];
  const float* look  = (const float*)d_in[1];
  const float* poses = (const float*)d_in[2];
  const float* Km    = (const float*)d_in[3];
  const float* invK  = (const float*)d_in[4];
  const float* dbins = (const float*)d_in[5];

  float* out_cost = (float*)d_out;
  float* out_miss = out_cost + (size_t)B_*D_*HW_;

  char*   ws    = (char*)d_ws;
  float*  mats  = (float*)ws;                                       // 128 floats
  __half* curH  = (__half*)(ws + 1024);                             // B*HW*C f16
  __half* lookH = (__half*)(ws + 1024 + (size_t)B_*HW_*C_*2);       // B*F*HW*C f16

  prep_kernel<<<(B_*HW_ + B_*F_*HW_)/128, 256, 0, stream>>>(
      cur, look, poses, Km, curH, lookH, mats);
  fused_kernel<<<B_*NCHUNK_, 512, 0, stream>>>(
      curH, lookH, mats, invK, dbins, out_cost, out_miss);
}